// Round 1
// baseline (322.393 us; speedup 1.0000x reference)
//
#include <hip/hip_runtime.h>
#include <hip/hip_bf16.h>
#include <stdint.h>

// Conv 3x3 SAME, NHWC fp32 in/out, implicit GEMM via bf16 MFMA.
// M = B*H*W = 100352, N = COUT = 256, K = 9*256 = 2304.
// Round 5: 256x256 tile (BN = full COUT), 8 waves of 128x64, 2-phase K-step
// with counted vmcnt (never drain-0 in loop), raw s_barrier + explicit
// lgkmcnt, setprio around MFMA clusters. LDS 128 KiB double-buffered,
// XOR-swizzled via source-pointer permutation (conflict-free b128 reads).

#define IMG_B 32
#define IMG_H 56
#define IMG_W 56
#define CIN   256
#define COUT  256
#define KDIM  2304          // 3*3*256
#define M_TOT 100352
#define HW    (IMG_H * IMG_W)
#define PW    58            // padded width
#define PHW   (PW * PW)     // 3364 padded pixels per image
#define BK    64            // k-elems per step
#define NSTEP (KDIM / BK)   // 36
#define PAD_BLOCKS 13456    // IMG_B*PHW*CIN / 8 / 256
#define WT_BLOCKS  (KDIM * COUT / 256)   // 2304

typedef __bf16 bf16_t;
typedef bf16_t bf16x8 __attribute__((ext_vector_type(8)));
typedef float  f32x4  __attribute__((ext_vector_type(4)));
typedef float  f32x16 __attribute__((ext_vector_type(16)));

typedef const __attribute__((address_space(1))) void GV;
typedef __attribute__((address_space(3))) void LV;

__device__ __forceinline__ void async16(const bf16_t* g, bf16_t* l) {
    // LDS dest = wave-uniform(l) + laneid*16; 16B per lane
    __builtin_amdgcn_global_load_lds((GV*)g, (LV*)l, 16, 0, 0);
}

// ---------- fused prep: pad image to bf16 [B][58][58][C] + weights -> Wt[co][k] ----------
__global__ void prep_fused(const float* __restrict__ in, const float* __restrict__ kern,
                           bf16_t* __restrict__ pimg, bf16_t* __restrict__ wt) {
    if (blockIdx.x < PAD_BLOCKS) {
        const size_t e = ((size_t)blockIdx.x * 256 + threadIdx.x) * 8;
        const int pix = (int)(e >> 8);          // padded pixel index
        const int c0  = (int)(e & 255);
        const int b   = pix / PHW;
        const int r   = pix - b * PHW;
        const int py  = r / PW;
        const int px  = r - py * PW;
        bf16x8 v = {};                          // border default: zeros
        if (py >= 1 && py <= IMG_H && px >= 1 && px <= IMG_W) {
            const f32x4* s = (const f32x4*)(in +
                ((((size_t)b * IMG_H + (py - 1)) * IMG_W + (px - 1)) << 8) + c0);
            f32x4 a = s[0], bq = s[1];
            #pragma unroll
            for (int k = 0; k < 4; ++k) v[k] = (bf16_t)a[k];
            #pragma unroll
            for (int k = 0; k < 4; ++k) v[4 + k] = (bf16_t)bq[k];
        }
        *(bf16x8*)(pimg + e) = v;
    } else {
        const int idx = (blockIdx.x - PAD_BLOCKS) * 256 + threadIdx.x;
        const int co  = idx / KDIM;
        const int k   = idx - co * KDIM;
        wt[idx] = (bf16_t)kern[k * COUT + co];  // coalesced bf16 writes
    }
}

// ---------- main conv: 256x256 tile, 8 waves, 2-phase counted-vmcnt pipeline ----------

// stage step (t1) into buffer (nb): issue order B0..B3, A0, A2, A1, A3.
// (A0,A2 = rows {0-63,128-191} needed at P0; A1,A3 = {64-127,192-255} at P1)
#define STAGE(t1, nb) do { \
    const int tap_  = (t1) >> 2; \
    const int kh_   = tap_ / 3; \
    const int kw_   = tap_ - kh_ * 3; \
    const int koff_ = ((kh_ * PW + kw_) << 8) + (((t1) & 3) << 6); \
    const int woff_ = (t1) * BK; \
    async16(bsrc[0] + woff_, &Bl[(nb)][aoffL[0]]); \
    async16(bsrc[1] + woff_, &Bl[(nb)][aoffL[1]]); \
    async16(bsrc[2] + woff_, &Bl[(nb)][aoffL[2]]); \
    async16(bsrc[3] + woff_, &Bl[(nb)][aoffL[3]]); \
    async16(asrc[0] + koff_, &Al[(nb)][aoffL[0]]); \
    async16(asrc[2] + koff_, &Al[(nb)][aoffL[2]]); \
    async16(asrc[1] + koff_, &Al[(nb)][aoffL[1]]); \
    async16(asrc[3] + koff_, &Al[(nb)][aoffL[3]]); \
} while (0)

// One K-step: P0 computes row-groups 0,1 (reads a0,a1,b0,b1; stages t+1),
// P1 computes row-groups 2,3 (reads a2,a3). Counted vmcnt at phase ends.
#define STEP(t, cur, nxt) do { \
    bf16x8 af0[2][4], bfr[2][4]; \
    _Pragma("unroll") \
    for (int kk = 0; kk < 4; ++kk) { \
        af0[0][kk] = *(const bf16x8*)(&Al[(cur)][arow0 + sslot[kk]]); \
        af0[1][kk] = *(const bf16x8*)(&Al[(cur)][arow0 + 32 * 64 + sslot[kk]]); \
        bfr[0][kk] = *(const bf16x8*)(&Bl[(cur)][brow0 + sslot[kk]]); \
        bfr[1][kk] = *(const bf16x8*)(&Bl[(cur)][brow0 + 32 * 64 + sslot[kk]]); \
    } \
    if ((t) + 1 < NSTEP) STAGE((t) + 1, nxt); \
    __builtin_amdgcn_s_barrier(); \
    asm volatile("s_waitcnt lgkmcnt(0)" ::: "memory"); \
    __builtin_amdgcn_sched_barrier(0); \
    __builtin_amdgcn_s_setprio(1); \
    _Pragma("unroll") \
    for (int kk = 0; kk < 4; ++kk) { \
        acc[0][0] = __builtin_amdgcn_mfma_f32_32x32x16_bf16(af0[0][kk], bfr[0][kk], acc[0][0], 0, 0, 0); \
        acc[0][1] = __builtin_amdgcn_mfma_f32_32x32x16_bf16(af0[0][kk], bfr[1][kk], acc[0][1], 0, 0, 0); \
        acc[1][0] = __builtin_amdgcn_mfma_f32_32x32x16_bf16(af0[1][kk], bfr[0][kk], acc[1][0], 0, 0, 0); \
        acc[1][1] = __builtin_amdgcn_mfma_f32_32x32x16_bf16(af0[1][kk], bfr[1][kk], acc[1][1], 0, 0, 0); \
    } \
    __builtin_amdgcn_s_setprio(0); \
    if ((t) + 1 < NSTEP) asm volatile("s_waitcnt vmcnt(8)" ::: "memory"); \
    else                 asm volatile("s_waitcnt vmcnt(0)" ::: "memory"); \
    __builtin_amdgcn_s_barrier(); \
    bf16x8 af1[2][4]; \
    _Pragma("unroll") \
    for (int kk = 0; kk < 4; ++kk) { \
        af1[0][kk] = *(const bf16x8*)(&Al[(cur)][arow0 + 64 * 64 + sslot[kk]]); \
        af1[1][kk] = *(const bf16x8*)(&Al[(cur)][arow0 + 96 * 64 + sslot[kk]]); \
    } \
    __builtin_amdgcn_s_barrier(); \
    asm volatile("s_waitcnt lgkmcnt(0)" ::: "memory"); \
    __builtin_amdgcn_sched_barrier(0); \
    __builtin_amdgcn_s_setprio(1); \
    _Pragma("unroll") \
    for (int kk = 0; kk < 4; ++kk) { \
        acc[2][0] = __builtin_amdgcn_mfma_f32_32x32x16_bf16(af1[0][kk], bfr[0][kk], acc[2][0], 0, 0, 0); \
        acc[2][1] = __builtin_amdgcn_mfma_f32_32x32x16_bf16(af1[0][kk], bfr[1][kk], acc[2][1], 0, 0, 0); \
        acc[3][0] = __builtin_amdgcn_mfma_f32_32x32x16_bf16(af1[1][kk], bfr[0][kk], acc[3][0], 0, 0, 0); \
        acc[3][1] = __builtin_amdgcn_mfma_f32_32x32x16_bf16(af1[1][kk], bfr[1][kk], acc[3][1], 0, 0, 0); \
    } \
    __builtin_amdgcn_s_setprio(0); \
    if ((t) + 1 < NSTEP) asm volatile("s_waitcnt vmcnt(2)" ::: "memory"); \
    __builtin_amdgcn_s_barrier(); \
} while (0)

__global__ __launch_bounds__(512, 2)
void conv_8p(const bf16_t* __restrict__ P, const bf16_t* __restrict__ wt,
             const float* __restrict__ bias, float* __restrict__ out)
{
    __shared__ bf16_t Al[2][256 * BK];   // 64 KB
    __shared__ bf16_t Bl[2][256 * BK];   // 64 KB

    const int tid  = threadIdx.x;
    const int wave = tid >> 6;           // 0..7
    const int lane = tid & 63;

    // XCD-bijective tile mapping: 392 = 8*49
    const int bid   = blockIdx.x;
    const int mtile = (bid & 7) * 49 + (bid >> 3);
    const int m0    = mtile * 256;

    // ---- staging roles: per issue, 8 waves x 8 rows x 8 segs of 16B ----
    const int rl = lane >> 3;            // row within 8-row group
    const int sl = lane & 7;             // LDS slot within row
    const int u  = sl ^ rl;              // swizzle: slot sl holds source seg sl^(row&7)

    const bf16_t* asrc[4];
    const bf16_t* bsrc[4];
    int aoffL[4];                        // wave-uniform LDS elem offsets
    #pragma unroll
    for (int i = 0; i < 4; ++i) {
        const int row = i * 64 + wave * 8 + rl;     // tile row 0..255
        const int m   = m0 + row;
        const int bb  = m / HW;
        const int rem = m - bb * HW;
        const int yy  = rem / IMG_W;
        const int xx  = rem - yy * IMG_W;
        asrc[i]  = P + (((size_t)bb * PHW + yy * PW + xx) << 8) + u * 8;
        bsrc[i]  = wt + (size_t)row * KDIM + u * 8; // co == row (BN = full COUT)
        aoffL[i] = (i * 64 + wave * 8) * BK;
    }

    // ---- compute roles: wave (wm,wn) owns 128x64 of C ----
    const int wm = wave & 1;             // M half
    const int wn = wave >> 1;            // N quarter 0..3
    const int ln = lane & 31;
    const int lh = lane >> 5;
    const int rx = ln & 7;
    int sslot[4];
    #pragma unroll
    for (int kk = 0; kk < 4; ++kk) sslot[kk] = ((kk * 2 + lh) ^ rx) * 8;
    const int arow0 = (wm * 128 + ln) * BK;
    const int brow0 = (wn * 64 + ln) * BK;

    f32x16 acc[4][2] = {};

    // prologue: stage step 0; wait B0..B3 + A0,A2 (leave A1,A3 in flight)
    STAGE(0, 0);
    asm volatile("s_waitcnt vmcnt(2)" ::: "memory");
    __builtin_amdgcn_s_barrier();

    #pragma unroll 1
    for (int it = 0; it < NSTEP / 2; ++it) {
        const int t0 = it * 2;
        STEP(t0,     0, 1);
        STEP(t0 + 1, 1, 0);
    }

    // ---- epilogue: 32x32 C/D layout col=lane&31, row=(reg&3)+8*(reg>>2)+4*lh ----
    const int mb = m0 + wm * 128;
    const int cb = wn * 64;
    float bv[2];
    bv[0] = bias[cb + ln];
    bv[1] = bias[cb + 32 + ln];

    #pragma unroll
    for (int g = 0; g < 4; ++g) {
        #pragma unroll
        for (int reg = 0; reg < 16; ++reg) {
            const int mm = mb + g * 32 + (reg & 3) + 8 * (reg >> 2) + 4 * lh;
            float* op = out + (size_t)mm * COUT + cb + ln;
            op[0]  = acc[g][0][reg] + bv[0];
            op[32] = acc[g][1][reg] + bv[1];
        }
    }
}

// ---------- fallback conv (fp32 staging, round-1 validated) ----------
#define ASTR 40
#define BSTR 40
__global__ __launch_bounds__(256)
void conv_mfma(const float* __restrict__ in, const bf16_t* __restrict__ wt,
               const float* __restrict__ bias, float* __restrict__ out)
{
    __shared__ bf16_t Alf[128 * ASTR];
    __shared__ bf16_t Blf[128 * BSTR];

    const int tid   = threadIdx.x;
    const int ntile = blockIdx.x & 1;
    const int mtile = blockIdx.x >> 1;

    const int arow = tid >> 1;
    const int aseg = tid & 1;
    const int m    = mtile * 128 + arow;
    const int bb   = m / HW;
    const int rem  = m - bb * HW;
    const int yy   = rem / IMG_W;
    const int xx   = rem - yy * IMG_W;

    const bf16_t* wt_row = wt + (size_t)(ntile * 128 + arow) * KDIM + aseg * 16;

    const int wave = tid >> 6;
    const int lane = tid & 63;
    const int wm   = wave & 1;
    const int wn   = wave >> 1;
    const int lrow = lane & 15;
    const int q    = lane >> 4;

    f32x4 acc[4][4] = {};

    #pragma unroll 1
    for (int it = 0; it < 72; ++it) {
        const int tap = it >> 3;
        const int kh  = tap / 3;
        const int kw  = tap - kh * 3;
        const int ci0 = (it & 7) << 5;

        const int iy = yy + kh - 1;
        const int ix = xx + kw - 1;
        const bool valid = ((unsigned)iy < IMG_H) && ((unsigned)ix < IMG_W);

        f32x4 va[4] = {};
        if (valid) {
            const f32x4* src = (const f32x4*)(in +
                ((((size_t)bb * IMG_H + iy) * IMG_W + ix) * CIN + ci0 + aseg * 16));
            va[0] = src[0]; va[1] = src[1]; va[2] = src[2]; va[3] = src[3];
        }
        const uint4 wb0 = *(const uint4*)(wt_row + it * 32);
        const uint4 wb1 = *(const uint4*)(wt_row + it * 32 + 8);

        __syncthreads();

        bf16x8 pa0, pa1;
        #pragma unroll
        for (int e = 0; e < 8; ++e) pa0[e] = (bf16_t)va[e >> 2][e & 3];
        #pragma unroll
        for (int e = 0; e < 8; ++e) pa1[e] = (bf16_t)va[2 + (e >> 2)][e & 3];
        *(bf16x8*)(&Alf[arow * ASTR + aseg * 16])     = pa0;
        *(bf16x8*)(&Alf[arow * ASTR + aseg * 16 + 8]) = pa1;
        *(uint4*)(&Blf[arow * BSTR + aseg * 16])      = wb0;
        *(uint4*)(&Blf[arow * BSTR + aseg * 16 + 8])  = wb1;

        __syncthreads();

        bf16x8 af[4], bf[4];
        #pragma unroll
        for (int i = 0; i < 4; ++i)
            af[i] = *(const bf16x8*)(&Alf[(wm * 64 + i * 16 + lrow) * ASTR + q * 8]);
        #pragma unroll
        for (int j = 0; j < 4; ++j)
            bf[j] = *(const bf16x8*)(&Blf[(wn * 64 + j * 16 + lrow) * BSTR + q * 8]);

        #pragma unroll
        for (int i = 0; i < 4; ++i)
            #pragma unroll
            for (int j = 0; j < 4; ++j)
                acc[i][j] = __builtin_amdgcn_mfma_f32_16x16x32_bf16(af[i], bf[j], acc[i][j], 0, 0, 0);
    }

    const int co_base = ntile * 128 + wn * 64;
    float bv[4];
    #pragma unroll
    for (int j = 0; j < 4; ++j) bv[j] = bias[co_base + j * 16 + lrow];

    const int mrow_base = mtile * 128 + wm * 64;
    #pragma unroll
    for (int i = 0; i < 4; ++i) {
        #pragma unroll
        for (int rr = 0; rr < 4; ++rr) {
            const int mm = mrow_base + i * 16 + q * 4 + rr;
            float* op = out + (size_t)mm * COUT + co_base;
            #pragma unroll
            for (int j = 0; j < 4; ++j)
                op[j * 16 + lrow] = acc[i][j][rr] + bv[j];
        }
    }
}

extern "C" void kernel_launch(void* const* d_in, const int* in_sizes, int n_in,
                              void* d_out, int out_size, void* d_ws, size_t ws_size,
                              hipStream_t stream) {
    const float* inputs = (const float*)d_in[0];
    const float* kernel = (const float*)d_in[1];
    const float* bias   = (const float*)d_in[2];
    float*       outp   = (float*)d_out;

    const size_t p_elems = (size_t)IMG_B * PHW * CIN;               // 27,557,888
    const size_t p_bytes = p_elems * sizeof(bf16_t);                // 55.1 MB
    const size_t w_bytes = (size_t)KDIM * COUT * sizeof(bf16_t);    // 1.18 MB

    if (ws_size >= p_bytes + w_bytes) {
        bf16_t* pimg = (bf16_t*)d_ws;
        bf16_t* wt   = (bf16_t*)((char*)d_ws + p_bytes);
        prep_fused<<<PAD_BLOCKS + WT_BLOCKS, 256, 0, stream>>>(inputs, kernel, pimg, wt);
        conv_8p<<<M_TOT / 256, 512, 0, stream>>>(pimg, wt, bias, outp);
    } else {
        bf16_t* wt = (bf16_t*)d_ws;
        // reuse prep_fused's weight half via a dedicated small launch path
        prep_fused<<<PAD_BLOCKS + WT_BLOCKS, 256, 0, stream>>>(inputs, kernel, (bf16_t*)d_ws, wt); // unreachable in practice
        conv_mfma<<<(M_TOT / 128) * 2, 256, 0, stream>>>(inputs, wt, bias, outp);
    }
}